// Round 9
// baseline (1394.413 us; speedup 1.0000x reference)
//
#include <hip/hip_runtime.h>

// ---------------------------------------------------------------------------
// GIN 2-layer forward (bf16 features, MFMA GEMMs, CSR gather segment-sum):
//   CSR bucket edges by dst (hist -> parallel scan -> fill)
//   p1 = bf16( x @ w1a )                      [b1a cancels in BN]
//   s1 = bf16( p1[n] + gather-sum )           (fused column stats)
//   h1 = bf16( relu( relu(sc1*s1+sh1) @ w1b + b1b ) )
//   p2 = bf16( h1 @ w2a )                     [b2a cancels in BN]
//   s2 = bf16( p2[n] + gather-sum )           (fused stats)
//   out = log_softmax( relu(sc2*s2+sh2) @ w2b + b2b )  fp32, fused epilogue
// segsum_vg: VECTOR-GROUP gather -- lane groups of 16 (C=128) / 8 (C=64)
// each cover one full row via short8 (16B) loads => 4 / 8 edges per gather
// INSTRUCTION. Attacks the measured per-VMEM-instruction latency wall
// (R5-R7: cost ~ instr count, not bytes). shfl_xor group reduce per node.
// ---------------------------------------------------------------------------

typedef unsigned short u16;
typedef unsigned int u32;
typedef __attribute__((ext_vector_type(8))) short short8;
typedef __attribute__((ext_vector_type(4))) short short4v;
typedef __attribute__((ext_vector_type(4))) float f32x4;

#define DEV_INLINE __device__ __forceinline__

DEV_INLINE void atomAddF(float* p, float v) { unsafeAtomicAdd(p, v); }

DEV_INLINE u16 f2bf(float f) {
    unsigned u = __float_as_uint(f);
    u += 0x7fffu + ((u >> 16) & 1u);   // round-to-nearest-even
    return (u16)(u >> 16);
}
DEV_INLINE float bf2f(u16 h) { return __uint_as_float(((unsigned)h) << 16); }

// ---------------------------------------------------------------------------
// Weight prep (all 4 weights, one launch): W[K][NOUT] fp32 -> frag-ordered
// bf16 (MFMA A-operand, swapped). unit=(ct,kc,lane): 8 bf16 for
// col=ct*16+(lane&15), k=kc*32+(lane>>4)*8+j.
// ---------------------------------------------------------------------------
__global__ __launch_bounds__(256) void wprep4_k(
    const float* __restrict__ w1a, const float* __restrict__ w1b,
    const float* __restrict__ w2a, const float* __restrict__ w2b,
    short* __restrict__ o1a, short* __restrict__ o1b,
    short* __restrict__ o2a, short* __restrict__ o2b)
{
    int b = blockIdx.x;
    const float* W; short* wf; int K, NOUT;
    if (b < 8)       { W = w1a; wf = o1a; K = 128; NOUT = 128; }
    else if (b < 16) { W = w1b; wf = o1b; K = 128; NOUT = 128; b -= 8; }
    else if (b < 20) { W = w2a; wf = o2a; K = 128; NOUT = 64;  b -= 16; }
    else             { W = w2b; wf = o2b; K = 64;  NOUT = 64;  b -= 20; }
    const int u = b * 256 + threadIdx.x;
    const int units = (NOUT / 16) * (K / 32) * 64;
    if (u >= units) return;
    const int per_ct = (K / 32) * 64;
    const int ct = u / per_ct;
    const int rem = u % per_ct;
    const int kc = rem >> 6;
    const int l = rem & 63;
    const int col = ct * 16 + (l & 15);
    const int k0 = kc * 32 + (l >> 4) * 8;
    short8 pk;
#pragma unroll
    for (int j = 0; j < 8; j++)
        pk[j] = (short)f2bf(W[(size_t)(k0 + j) * NOUT + col]);
    *(short8*)&wf[(size_t)u * 8] = pk;
}

// ---------------------------------------------------------------------------
// MFMA GEMM (swapped operands => per-lane contiguous C-writes):
//   out[M][NC] = f(A[M][KD]) @ W  (+bias) (+relu | +row log_softmax)
// A is fp32 or bf16; out is bf16 or fp32. BM=128 rows, 256 threads (4 waves).
// ---------------------------------------------------------------------------
template <int KD, int NC, bool ABF16, bool BNIN, bool BIAS, bool RELUOUT,
          bool LOGSM, bool OBF16>
__global__ __launch_bounds__(256) void mgemm(
    const void* __restrict__ Ap, const short* __restrict__ Wf,
    const float* __restrict__ sc, const float* __restrict__ sh,
    const float* __restrict__ bias, void* __restrict__ outp, int M)
{
    constexpr int BM = 128;
    constexpr int KC = KD / 32;   // 32-wide k chunks
    constexpr int CT = NC / 16;   // 16-wide col tiles
    __shared__ short Asl[BM * KD];
    __shared__ short Bsl[NC * KD];

    const int t = threadIdx.x;
    const int l = t & 63;
    const int w = t >> 6;

    // ---- stage B: frag-ordered weights, linear copy ----
    {
        const float4* src = (const float4*)Wf;
        float4* dst = (float4*)Bsl;
        constexpr int NU = NC * KD / 8;
#pragma unroll
        for (int u = t; u < NU; u += 256) dst[u] = src[u];
    }
    // ---- stage A: 2 threads per row -> (BN+ReLU) -> bf16 frags ----
    {
        const int r = t >> 1;
        const int half = t & 1;
        const int grow = blockIdx.x * BM + r;
        const int rt = r >> 4;
        constexpr int KH = KD / 2;
        u16 hv[KH];
        if (grow < M) {
            if constexpr (ABF16) {
                const u16* ap = (const u16*)Ap + (size_t)grow * KD + half * KH;
#pragma unroll
                for (int i = 0; i < KH / 8; i++)
                    *(short8*)&hv[i * 8] = ((const short8*)ap)[i];
                if constexpr (BNIN) {
#pragma unroll
                    for (int i = 0; i < KH; i++) {
                        const int k = half * KH + i;
                        hv[i] = f2bf(fmaxf(0.f, bf2f(hv[i]) * sc[k] + sh[k]));
                    }
                }
            } else {
                const float* ap = (const float*)Ap + (size_t)grow * KD + half * KH;
#pragma unroll
                for (int i = 0; i < KH / 4; i++) {
                    const float4 v = ((const float4*)ap)[i];
                    float f0 = v.x, f1 = v.y, f2 = v.z, f3 = v.w;
                    if constexpr (BNIN) {
                        const int k = half * KH + i * 4;
                        f0 = fmaxf(0.f, f0 * sc[k + 0] + sh[k + 0]);
                        f1 = fmaxf(0.f, f1 * sc[k + 1] + sh[k + 1]);
                        f2 = fmaxf(0.f, f2 * sc[k + 2] + sh[k + 2]);
                        f3 = fmaxf(0.f, f3 * sc[k + 3] + sh[k + 3]);
                    }
                    hv[i * 4 + 0] = f2bf(f0); hv[i * 4 + 1] = f2bf(f1);
                    hv[i * 4 + 2] = f2bf(f2); hv[i * 4 + 3] = f2bf(f3);
                }
            }
        } else {
#pragma unroll
            for (int i = 0; i < KH; i++) hv[i] = 0;
        }
#pragma unroll
        for (int g = 0; g < KH / 8; g++) {
            const int k0 = half * KH + g * 8;
            const int kc = k0 >> 5;
            const int lane = (r & 15) + ((k0 >> 3) & 3) * 16;
            *(short8*)&Asl[((rt * KC + kc) * 64 + lane) * 8] =
                *(short8*)&hv[g * 8];
        }
    }
    __syncthreads();

    // ---- MFMA: wave w owns row-tiles {2w, 2w+1} x all col-tiles ----
    const int rt0 = w * 2;
    f32x4 acc[2][CT];
#pragma unroll
    for (int i = 0; i < 2; i++)
#pragma unroll
        for (int c = 0; c < CT; c++) acc[i][c] = (f32x4){0.f, 0.f, 0.f, 0.f};

#pragma unroll
    for (int kc = 0; kc < KC; kc++) {
        const short8 x0 = *(const short8*)&Asl[((rt0 * KC + kc) * 64 + l) * 8];
        const short8 x1 = *(const short8*)&Asl[(((rt0 + 1) * KC + kc) * 64 + l) * 8];
#pragma unroll
        for (int ct = 0; ct < CT; ct++) {
            const short8 wb = *(const short8*)&Bsl[((ct * KC + kc) * 64 + l) * 8];
            acc[0][ct] = __builtin_amdgcn_mfma_f32_16x16x32_bf16(wb, x0, acc[0][ct], 0, 0, 0);
            acc[1][ct] = __builtin_amdgcn_mfma_f32_16x16x32_bf16(wb, x1, acc[1][ct], 0, 0, 0);
        }
    }

    // ---- epilogue: lane l holds row (l&15), cols (l>>4)*4+{0..3} of tile ----
    const int cbase = (l >> 4) * 4;
#pragma unroll
    for (int rr = 0; rr < 2; rr++) {
        const int grow = blockIdx.x * BM + (rt0 + rr) * 16 + (l & 15);
        if constexpr (!LOGSM) {
            if (grow < M) {
#pragma unroll
                for (int ct = 0; ct < CT; ct++) {
                    f32x4 o = acc[rr][ct];
                    if constexpr (BIAS) {
                        const float4 bv = *(const float4*)&bias[ct * 16 + cbase];
                        o[0] += bv.x; o[1] += bv.y; o[2] += bv.z; o[3] += bv.w;
                    }
                    if constexpr (RELUOUT) {
#pragma unroll
                        for (int j = 0; j < 4; j++) o[j] = fmaxf(o[j], 0.f);
                    }
                    if constexpr (OBF16) {
                        short4v o16;
#pragma unroll
                        for (int j = 0; j < 4; j++) o16[j] = (short)f2bf(o[j]);
                        *(short4v*)&((u16*)outp)[(size_t)grow * NC + ct * 16 + cbase] = o16;
                    } else {
                        *(f32x4*)&((float*)outp)[(size_t)grow * NC + ct * 16 + cbase] = o;
                    }
                }
            }
        } else {
            // fused row log_softmax (row spread across lanes l, l^16, l^32, l^48)
            float v[CT * 4];
#pragma unroll
            for (int ct = 0; ct < CT; ct++) {
                const float4 bv = *(const float4*)&bias[ct * 16 + cbase];
                v[ct * 4 + 0] = acc[rr][ct][0] + bv.x;
                v[ct * 4 + 1] = acc[rr][ct][1] + bv.y;
                v[ct * 4 + 2] = acc[rr][ct][2] + bv.z;
                v[ct * 4 + 3] = acc[rr][ct][3] + bv.w;
            }
            float m = v[0];
#pragma unroll
            for (int j = 1; j < CT * 4; j++) m = fmaxf(m, v[j]);
            m = fmaxf(m, __shfl_xor(m, 16));
            m = fmaxf(m, __shfl_xor(m, 32));
            float s = 0.f;
#pragma unroll
            for (int j = 0; j < CT * 4; j++) s += __expf(v[j] - m);
            s += __shfl_xor(s, 16);
            s += __shfl_xor(s, 32);
            const float lg = m + __logf(s);
            if (grow < M) {
#pragma unroll
                for (int ct = 0; ct < CT; ct++) {
                    f32x4 o;
#pragma unroll
                    for (int j = 0; j < 4; j++) o[j] = v[ct * 4 + j] - lg;
                    *(f32x4*)&((float*)outp)[(size_t)grow * NC + ct * 16 + cbase] = o;
                }
            }
        }
    }
}

// ---------------------------------------------------------------------------
// CSR build: histogram, 3-kernel parallel exclusive scan, bucket fill.
// ---------------------------------------------------------------------------
__global__ __launch_bounds__(256) void hist_k(const int* __restrict__ ei,
                                              int* __restrict__ cnt, int E)
{
    const int gid = blockIdx.x * blockDim.x + threadIdx.x;
    const int stride = gridDim.x * blockDim.x;
    for (int e = gid; e < E; e += stride) atomicAdd(&cnt[ei[E + e]], 1);
}

__global__ __launch_bounds__(256) void bsum_k(const int* __restrict__ cnt,
                                              int* __restrict__ bsum, int N)
{
    __shared__ int ws[4];
    const int i = blockIdx.x * 256 + threadIdx.x;
    int v = (i < N) ? cnt[i] : 0;
    for (int d = 32; d; d >>= 1) v += __shfl_xor(v, d, 64);
    if ((threadIdx.x & 63) == 0) ws[threadIdx.x >> 6] = v;
    __syncthreads();
    if (threadIdx.x == 0) bsum[blockIdx.x] = ws[0] + ws[1] + ws[2] + ws[3];
}

// single block; G1 <= 256
__global__ __launch_bounds__(256) void bscan_k(const int* __restrict__ bsum,
                                               int* __restrict__ bpre, int G1)
{
    __shared__ int part[256];
    const int t = threadIdx.x;
    const int v = (t < G1) ? bsum[t] : 0;
    part[t] = v;
    __syncthreads();
    for (int d = 1; d < 256; d <<= 1) {
        const int u = (t >= d) ? part[t - d] : 0;
        __syncthreads();
        part[t] += u;
        __syncthreads();
    }
    bpre[t] = part[t] - v;   // exclusive
}

__global__ __launch_bounds__(256) void offs_k(const int* __restrict__ cnt,
                                              const int* __restrict__ bpre,
                                              int* __restrict__ off,
                                              int* __restrict__ cursor,
                                              int N, int E)
{
    __shared__ int part[256];
    const int t = threadIdx.x;
    const int i = blockIdx.x * 256 + t;
    const int v = (i < N) ? cnt[i] : 0;
    part[t] = v;
    __syncthreads();
    for (int d = 1; d < 256; d <<= 1) {
        const int u = (t >= d) ? part[t - d] : 0;
        __syncthreads();
        part[t] += u;
        __syncthreads();
    }
    if (i < N) {
        const int o = bpre[blockIdx.x] + part[t] - v;
        off[i] = o;
        cursor[i] = o;
    }
    if (blockIdx.x == 0 && t == 0) off[N] = E;
}

__global__ __launch_bounds__(256) void fill_k(const int* __restrict__ ei,
                                              int* __restrict__ cursor,
                                              int* __restrict__ srcs, int E)
{
    const int gid = blockIdx.x * blockDim.x + threadIdx.x;
    const int stride = gridDim.x * blockDim.x;
    for (int e = gid; e < E; e += stride) {
        const int s = ei[e];
        const int d = ei[E + e];
        const int pos = atomicAdd(&cursor[d], 1);
        srcs[pos] = s;
    }
}

// ---------------------------------------------------------------------------
// Vector-group gather segment-sum (bf16 in/out) + fused column stats.
// Lane group of LPR lanes covers one row via short8 (16B) loads:
//   C=128: LPR=16, G=4 edges per gather instruction
//   C=64 : LPR=8,  G=8 edges per gather instruction
// One wave per node (4 consecutive nodes per wave). Group indices from one
// vector load (broadcast within group), prefetched one iteration ahead.
// Node total via shfl_xor over group dim; lanes [0,LPR) write + do stats.
// ---------------------------------------------------------------------------
template <int C>
__global__ __launch_bounds__(256) void segsum_vg(
    const u16* __restrict__ p, const int* __restrict__ off,
    const int* __restrict__ srcs, u16* __restrict__ out,
    float* __restrict__ sum, float* __restrict__ sumsq, int N)
{
    constexpr int LPR = (C == 128) ? 16 : 8;   // lanes per row
    constexpr int G   = 64 / LPR;              // edges per gather instr
    constexpr int LOG = (C == 128) ? 4 : 3;
    constexpr int NPW = 4;                     // nodes per wave
    __shared__ float redS[4][LPR * 8];
    __shared__ float redQ[4][LPR * 8];

    const int tid = threadIdx.x;
    const int wv = tid >> 6;
    const int l = tid & 63;
    const int gid = l >> LOG;          // group id in [0, G)
    const int sub = l & (LPR - 1);     // lane within row
    const int nbase = (blockIdx.x * 4 + wv) * NPW;

    float ss[8], qq[8];
#pragma unroll
    for (int j = 0; j < 8; j++) { ss[j] = 0.f; qq[j] = 0.f; }

    for (int i = 0; i < NPW; i++) {
        const int n = nbase + i;
        if (n >= N) break;
        const int lo = __builtin_amdgcn_readfirstlane(off[n]);
        const int hi = __builtin_amdgcn_readfirstlane(off[n + 1]);

        // self row (issued early; consumed after the reduce)
        const short8 selfv = *(const short8*)&p[(size_t)n * C + sub * 8];

        float acc[8];
#pragma unroll
        for (int j = 0; j < 8; j++) acc[j] = 0.f;

        if (lo < hi) {
            int e = lo;
            int sc_ = srcs[min(e + gid, hi - 1)];
            while (e < hi) {
                const short8 v = *(const short8*)&p[(size_t)sc_ * C + sub * 8];
                const int sn_ = srcs[min(e + G + gid, hi - 1)];  // prefetch
                if (e + G <= hi) {                // full group (common path)
#pragma unroll
                    for (int j = 0; j < 8; j++) acc[j] += bf2f((u16)v[j]);
                } else {                          // masked tail
                    const bool live = (e + gid) < hi;
#pragma unroll
                    for (int j = 0; j < 8; j++)
                        acc[j] += live ? bf2f((u16)v[j]) : 0.f;
                }
                sc_ = sn_;
                e += G;
            }
        }

        // reduce over the G row-groups (xor over bits >= LOG)
#pragma unroll
        for (int o = LPR; o < 64; o <<= 1)
#pragma unroll
            for (int j = 0; j < 8; j++) acc[j] += __shfl_xor(acc[j], o);

        // lanes [0, LPR): add self, round, write, stats
        if (l < LPR) {
            short8 r8;
#pragma unroll
            for (int j = 0; j < 8; j++) {
                const float val = acc[j] + bf2f((u16)selfv[j]);
                const u16 r = f2bf(val);
                r8[j] = (short)r;
                const float f = bf2f(r);
                ss[j] += f;
                qq[j] += f * f;
            }
            *(short8*)&out[(size_t)n * C + sub * 8] = r8;
        }
    }

    // block reduce: per-wave partials -> wave 0 -> one atomic per channel
    if (l < LPR) {
#pragma unroll
        for (int j = 0; j < 8; j++) {
            redS[wv][sub * 8 + j] = ss[j];
            redQ[wv][sub * 8 + j] = qq[j];
        }
    }
    __syncthreads();
    if (wv == 0 && l < LPR) {
#pragma unroll
        for (int j = 0; j < 8; j++) {
            float a = 0.f, b = 0.f;
#pragma unroll
            for (int w2 = 0; w2 < 4; w2++) {
                a += redS[w2][sub * 8 + j];
                b += redQ[w2][sub * 8 + j];
            }
            atomAddF(&sum[sub * 8 + j], a);
            atomAddF(&sumsq[sub * 8 + j], b);
        }
    }
}

__global__ void bnfinal_k(const float* __restrict__ sum,
                          const float* __restrict__ sumsq,
                          const float* __restrict__ g,
                          const float* __restrict__ be,
                          float* __restrict__ sc, float* __restrict__ sh,
                          int C, float invN)
{
    const int c = threadIdx.x;
    if (c < C) {
        const float m = sum[c] * invN;
        const float v = sumsq[c] * invN - m * m;
        const float r = rsqrtf(v + 1e-5f);
        const float s = g[c] * r;
        sc[c] = s;
        sh[c] = be[c] - m * s;
    }
}

extern "C" void kernel_launch(void* const* d_in, const int* in_sizes, int n_in,
                              void* d_out, int out_size, void* d_ws, size_t ws_size,
                              hipStream_t stream)
{
    const float* x   = (const float*)d_in[0];
    const int*   ei  = (const int*)d_in[1];
    const float* w1a = (const float*)d_in[2];
    // d_in[3] = b1a: cancelled by BN
    const float* g1  = (const float*)d_in[4];
    const float* be1 = (const float*)d_in[5];
    const float* w1b = (const float*)d_in[6];
    const float* b1b = (const float*)d_in[7];
    const float* w2a = (const float*)d_in[8];
    // d_in[9] = b2a: cancelled by BN
    const float* g2  = (const float*)d_in[10];
    const float* be2 = (const float*)d_in[11];
    const float* w2b = (const float*)d_in[12];
    const float* b2b = (const float*)d_in[13];
    float* out = (float*)d_out;

    const int N = in_sizes[0] / 128;   // 50000
    const int E = in_sizes[1] / 2;     // 800000

    // ---- workspace layout ----
    u16* buf1 = (u16*)d_ws;                      // N*128 bf16 : p1, then h1
    u16* buf2 = buf1 + (size_t)N * 128;          // N*128 bf16 : s1, then p2|s2
    float* stats = (float*)(buf2 + (size_t)N * 128);  // 1024 floats
    float* sum1 = stats,       *sq1 = stats + 128;
    float* sum2 = stats + 256, *sq2 = stats + 320;
    float* sc1  = stats + 384, *sh1 = stats + 512;
    float* sc2  = stats + 640, *sh2 = stats + 704;
    int* cnt    = (int*)(stats + 1024);          // N
    int* off    = cnt + N;                       // N+1
    int* cursor = off + N + 1;                   // N
    int* srcs   = cursor + N;                    // E
    int* bsum   = srcs + E;                      // 256
    int* bpre   = bsum + 256;                    // 256
    short* w1af = (short*)(bpre + 256);          // 128*128
    short* w1bf = w1af + 128 * 128;              // 128*128
    short* w2af = w1bf + 128 * 128;              // 128*64
    short* w2bf = w2af + 128 * 64;               // 64*64
    u16* p1 = buf1;
    u16* s1 = buf2;
    u16* h1 = buf1;                    // reuse: p1 dead after segsum1
    u16* p2 = buf2;                    // reuse: s1 dead after mgemm2 (N*64)
    u16* s2 = buf2 + (size_t)N * 64;   // upper half

    hipMemsetAsync(stats, 0, 1024 * sizeof(float) + (size_t)N * sizeof(int), stream);

    const int G1 = (N + 255) / 256;
    const int gb = (N + 127) / 128;
    const int gs = (N + 15) / 16;      // segsum_vg: 4 waves x 4 nodes per block

    // ---- CSR build ----
    hist_k<<<1024, 256, 0, stream>>>(ei, cnt, E);
    bsum_k<<<G1, 256, 0, stream>>>(cnt, bsum, N);
    bscan_k<<<1, 256, 0, stream>>>(bsum, bpre, G1);
    offs_k<<<G1, 256, 0, stream>>>(cnt, bpre, off, cursor, N, E);
    fill_k<<<1024, 256, 0, stream>>>(ei, cursor, srcs, E);

    // ---- weight prep (one launch for all four) ----
    wprep4_k<<<22, 256, 0, stream>>>(w1a, w1b, w2a, w2b, w1af, w1bf, w2af, w2bf);

    // ---- Layer 1 ----
    mgemm<128, 128, false, false, false, false, false, true>
        <<<gb, 256, 0, stream>>>(x, w1af, nullptr, nullptr, nullptr, p1, N);
    segsum_vg<128><<<gs, 256, 0, stream>>>(p1, off, srcs, s1, sum1, sq1, N);
    bnfinal_k<<<1, 128, 0, stream>>>(sum1, sq1, g1, be1, sc1, sh1, 128, 1.f / N);
    mgemm<128, 128, true, true, true, true, false, true>
        <<<gb, 256, 0, stream>>>(s1, w1bf, sc1, sh1, b1b, h1, N);

    // ---- Layer 2 (aggregate after projecting to 64ch) ----
    mgemm<128, 64, true, false, false, false, false, true>
        <<<gb, 256, 0, stream>>>(h1, w2af, nullptr, nullptr, nullptr, p2, N);
    segsum_vg<64><<<gs, 256, 0, stream>>>(p2, off, srcs, s2, sum2, sq2, N);
    bnfinal_k<<<1, 64, 0, stream>>>(sum2, sq2, g2, be2, sc2, sh2, 64, 1.f / N);
    mgemm<64, 64, true, true, true, false, true, false>
        <<<gb, 256, 0, stream>>>(s2, w2bf, sc2, sh2, b2b, out, N);
}

// Round 10
// 399.471 us; speedup vs baseline: 3.4907x; 3.4907x over previous
//
#include <hip/hip_runtime.h>

// ---------------------------------------------------------------------------
// GIN 2-layer forward (bf16 features, MFMA GEMMs, CSR gather segment-sum):
//   CSR bucket edges by dst (hist -> parallel scan -> fill)
//   p1 = bf16( x @ w1a )                      [b1a cancels in BN]
//   s1 = bf16( p1[n] + gather-sum )           (fused column stats)
//   h1 = bf16( relu( relu(sc1*s1+sh1) @ w1b + b1b ) )
//   p2 = bf16( h1 @ w2a )                     [b2a cancels in BN]
//   s2 = bf16( p2[n] + gather-sum )           (fused stats)
//   out = log_softmax( relu(sc2*s2+sh2) @ w2b + b2b )  fp32, fused epilogue
// segsum_as: wave-per-node, INLINE-ASM 8-deep gather pipeline --
// 8 volatile global_load_dword (SGPR row base + const lane offset), one
// s_waitcnt vmcnt(0) asm with all 8 results as "+v" operands (cannot be
// reordered), then predicated adds. Compiler-proof MLP = 8 per wave.
// ---------------------------------------------------------------------------

typedef unsigned short u16;
typedef unsigned int u32;
typedef __attribute__((ext_vector_type(8))) short short8;
typedef __attribute__((ext_vector_type(4))) short short4v;
typedef __attribute__((ext_vector_type(4))) float f32x4;

#define DEV_INLINE __device__ __forceinline__

DEV_INLINE void atomAddF(float* p, float v) { unsafeAtomicAdd(p, v); }

DEV_INLINE u16 f2bf(float f) {
    unsigned u = __float_as_uint(f);
    u += 0x7fffu + ((u >> 16) & 1u);   // round-to-nearest-even
    return (u16)(u >> 16);
}
DEV_INLINE float bf2f(u16 h) { return __uint_as_float(((unsigned)h) << 16); }

// ---------------------------------------------------------------------------
// Weight prep (all 4 weights, one launch): W[K][NOUT] fp32 -> frag-ordered
// bf16 (MFMA A-operand, swapped). unit=(ct,kc,lane): 8 bf16 for
// col=ct*16+(lane&15), k=kc*32+(lane>>4)*8+j.
// ---------------------------------------------------------------------------
__global__ __launch_bounds__(256) void wprep4_k(
    const float* __restrict__ w1a, const float* __restrict__ w1b,
    const float* __restrict__ w2a, const float* __restrict__ w2b,
    short* __restrict__ o1a, short* __restrict__ o1b,
    short* __restrict__ o2a, short* __restrict__ o2b)
{
    int b = blockIdx.x;
    const float* W; short* wf; int K, NOUT;
    if (b < 8)       { W = w1a; wf = o1a; K = 128; NOUT = 128; }
    else if (b < 16) { W = w1b; wf = o1b; K = 128; NOUT = 128; b -= 8; }
    else if (b < 20) { W = w2a; wf = o2a; K = 128; NOUT = 64;  b -= 16; }
    else             { W = w2b; wf = o2b; K = 64;  NOUT = 64;  b -= 20; }
    const int u = b * 256 + threadIdx.x;
    const int units = (NOUT / 16) * (K / 32) * 64;
    if (u >= units) return;
    const int per_ct = (K / 32) * 64;
    const int ct = u / per_ct;
    const int rem = u % per_ct;
    const int kc = rem >> 6;
    const int l = rem & 63;
    const int col = ct * 16 + (l & 15);
    const int k0 = kc * 32 + (l >> 4) * 8;
    short8 pk;
#pragma unroll
    for (int j = 0; j < 8; j++)
        pk[j] = (short)f2bf(W[(size_t)(k0 + j) * NOUT + col]);
    *(short8*)&wf[(size_t)u * 8] = pk;
}

// ---------------------------------------------------------------------------
// MFMA GEMM (swapped operands => per-lane contiguous C-writes):
//   out[M][NC] = f(A[M][KD]) @ W  (+bias) (+relu | +row log_softmax)
// A is fp32 or bf16; out is bf16 or fp32. BM=128 rows, 256 threads (4 waves).
// ---------------------------------------------------------------------------
template <int KD, int NC, bool ABF16, bool BNIN, bool BIAS, bool RELUOUT,
          bool LOGSM, bool OBF16>
__global__ __launch_bounds__(256) void mgemm(
    const void* __restrict__ Ap, const short* __restrict__ Wf,
    const float* __restrict__ sc, const float* __restrict__ sh,
    const float* __restrict__ bias, void* __restrict__ outp, int M)
{
    constexpr int BM = 128;
    constexpr int KC = KD / 32;   // 32-wide k chunks
    constexpr int CT = NC / 16;   // 16-wide col tiles
    __shared__ short Asl[BM * KD];
    __shared__ short Bsl[NC * KD];

    const int t = threadIdx.x;
    const int l = t & 63;
    const int w = t >> 6;

    // ---- stage B: frag-ordered weights, linear copy ----
    {
        const float4* src = (const float4*)Wf;
        float4* dst = (float4*)Bsl;
        constexpr int NU = NC * KD / 8;
#pragma unroll
        for (int u = t; u < NU; u += 256) dst[u] = src[u];
    }
    // ---- stage A: 2 threads per row -> (BN+ReLU) -> bf16 frags ----
    {
        const int r = t >> 1;
        const int half = t & 1;
        const int grow = blockIdx.x * BM + r;
        const int rt = r >> 4;
        constexpr int KH = KD / 2;
        u16 hv[KH];
        if (grow < M) {
            if constexpr (ABF16) {
                const u16* ap = (const u16*)Ap + (size_t)grow * KD + half * KH;
#pragma unroll
                for (int i = 0; i < KH / 8; i++)
                    *(short8*)&hv[i * 8] = ((const short8*)ap)[i];
                if constexpr (BNIN) {
#pragma unroll
                    for (int i = 0; i < KH; i++) {
                        const int k = half * KH + i;
                        hv[i] = f2bf(fmaxf(0.f, bf2f(hv[i]) * sc[k] + sh[k]));
                    }
                }
            } else {
                const float* ap = (const float*)Ap + (size_t)grow * KD + half * KH;
#pragma unroll
                for (int i = 0; i < KH / 4; i++) {
                    const float4 v = ((const float4*)ap)[i];
                    float f0 = v.x, f1 = v.y, f2 = v.z, f3 = v.w;
                    if constexpr (BNIN) {
                        const int k = half * KH + i * 4;
                        f0 = fmaxf(0.f, f0 * sc[k + 0] + sh[k + 0]);
                        f1 = fmaxf(0.f, f1 * sc[k + 1] + sh[k + 1]);
                        f2 = fmaxf(0.f, f2 * sc[k + 2] + sh[k + 2]);
                        f3 = fmaxf(0.f, f3 * sc[k + 3] + sh[k + 3]);
                    }
                    hv[i * 4 + 0] = f2bf(f0); hv[i * 4 + 1] = f2bf(f1);
                    hv[i * 4 + 2] = f2bf(f2); hv[i * 4 + 3] = f2bf(f3);
                }
            }
        } else {
#pragma unroll
            for (int i = 0; i < KH; i++) hv[i] = 0;
        }
#pragma unroll
        for (int g = 0; g < KH / 8; g++) {
            const int k0 = half * KH + g * 8;
            const int kc = k0 >> 5;
            const int lane = (r & 15) + ((k0 >> 3) & 3) * 16;
            *(short8*)&Asl[((rt * KC + kc) * 64 + lane) * 8] =
                *(short8*)&hv[g * 8];
        }
    }
    __syncthreads();

    // ---- MFMA: wave w owns row-tiles {2w, 2w+1} x all col-tiles ----
    const int rt0 = w * 2;
    f32x4 acc[2][CT];
#pragma unroll
    for (int i = 0; i < 2; i++)
#pragma unroll
        for (int c = 0; c < CT; c++) acc[i][c] = (f32x4){0.f, 0.f, 0.f, 0.f};

#pragma unroll
    for (int kc = 0; kc < KC; kc++) {
        const short8 x0 = *(const short8*)&Asl[((rt0 * KC + kc) * 64 + l) * 8];
        const short8 x1 = *(const short8*)&Asl[(((rt0 + 1) * KC + kc) * 64 + l) * 8];
#pragma unroll
        for (int ct = 0; ct < CT; ct++) {
            const short8 wb = *(const short8*)&Bsl[((ct * KC + kc) * 64 + l) * 8];
            acc[0][ct] = __builtin_amdgcn_mfma_f32_16x16x32_bf16(wb, x0, acc[0][ct], 0, 0, 0);
            acc[1][ct] = __builtin_amdgcn_mfma_f32_16x16x32_bf16(wb, x1, acc[1][ct], 0, 0, 0);
        }
    }

    // ---- epilogue: lane l holds row (l&15), cols (l>>4)*4+{0..3} of tile ----
    const int cbase = (l >> 4) * 4;
#pragma unroll
    for (int rr = 0; rr < 2; rr++) {
        const int grow = blockIdx.x * BM + (rt0 + rr) * 16 + (l & 15);
        if constexpr (!LOGSM) {
            if (grow < M) {
#pragma unroll
                for (int ct = 0; ct < CT; ct++) {
                    f32x4 o = acc[rr][ct];
                    if constexpr (BIAS) {
                        const float4 bv = *(const float4*)&bias[ct * 16 + cbase];
                        o[0] += bv.x; o[1] += bv.y; o[2] += bv.z; o[3] += bv.w;
                    }
                    if constexpr (RELUOUT) {
#pragma unroll
                        for (int j = 0; j < 4; j++) o[j] = fmaxf(o[j], 0.f);
                    }
                    if constexpr (OBF16) {
                        short4v o16;
#pragma unroll
                        for (int j = 0; j < 4; j++) o16[j] = (short)f2bf(o[j]);
                        *(short4v*)&((u16*)outp)[(size_t)grow * NC + ct * 16 + cbase] = o16;
                    } else {
                        *(f32x4*)&((float*)outp)[(size_t)grow * NC + ct * 16 + cbase] = o;
                    }
                }
            }
        } else {
            // fused row log_softmax (row spread across lanes l, l^16, l^32, l^48)
            float v[CT * 4];
#pragma unroll
            for (int ct = 0; ct < CT; ct++) {
                const float4 bv = *(const float4*)&bias[ct * 16 + cbase];
                v[ct * 4 + 0] = acc[rr][ct][0] + bv.x;
                v[ct * 4 + 1] = acc[rr][ct][1] + bv.y;
                v[ct * 4 + 2] = acc[rr][ct][2] + bv.z;
                v[ct * 4 + 3] = acc[rr][ct][3] + bv.w;
            }
            float m = v[0];
#pragma unroll
            for (int j = 1; j < CT * 4; j++) m = fmaxf(m, v[j]);
            m = fmaxf(m, __shfl_xor(m, 16));
            m = fmaxf(m, __shfl_xor(m, 32));
            float s = 0.f;
#pragma unroll
            for (int j = 0; j < CT * 4; j++) s += __expf(v[j] - m);
            s += __shfl_xor(s, 16);
            s += __shfl_xor(s, 32);
            const float lg = m + __logf(s);
            if (grow < M) {
#pragma unroll
                for (int ct = 0; ct < CT; ct++) {
                    f32x4 o;
#pragma unroll
                    for (int j = 0; j < 4; j++) o[j] = v[ct * 4 + j] - lg;
                    *(f32x4*)&((float*)outp)[(size_t)grow * NC + ct * 16 + cbase] = o;
                }
            }
        }
    }
}

// ---------------------------------------------------------------------------
// CSR build: histogram, 3-kernel parallel exclusive scan, bucket fill.
// ---------------------------------------------------------------------------
__global__ __launch_bounds__(256) void hist_k(const int* __restrict__ ei,
                                              int* __restrict__ cnt, int E)
{
    const int gid = blockIdx.x * blockDim.x + threadIdx.x;
    const int stride = gridDim.x * blockDim.x;
    for (int e = gid; e < E; e += stride) atomicAdd(&cnt[ei[E + e]], 1);
}

__global__ __launch_bounds__(256) void bsum_k(const int* __restrict__ cnt,
                                              int* __restrict__ bsum, int N)
{
    __shared__ int ws[4];
    const int i = blockIdx.x * 256 + threadIdx.x;
    int v = (i < N) ? cnt[i] : 0;
    for (int d = 32; d; d >>= 1) v += __shfl_xor(v, d, 64);
    if ((threadIdx.x & 63) == 0) ws[threadIdx.x >> 6] = v;
    __syncthreads();
    if (threadIdx.x == 0) bsum[blockIdx.x] = ws[0] + ws[1] + ws[2] + ws[3];
}

// single block; G1 <= 256
__global__ __launch_bounds__(256) void bscan_k(const int* __restrict__ bsum,
                                               int* __restrict__ bpre, int G1)
{
    __shared__ int part[256];
    const int t = threadIdx.x;
    const int v = (t < G1) ? bsum[t] : 0;
    part[t] = v;
    __syncthreads();
    for (int d = 1; d < 256; d <<= 1) {
        const int u = (t >= d) ? part[t - d] : 0;
        __syncthreads();
        part[t] += u;
        __syncthreads();
    }
    bpre[t] = part[t] - v;   // exclusive
}

__global__ __launch_bounds__(256) void offs_k(const int* __restrict__ cnt,
                                              const int* __restrict__ bpre,
                                              int* __restrict__ off,
                                              int* __restrict__ cursor,
                                              int N, int E)
{
    __shared__ int part[256];
    const int t = threadIdx.x;
    const int i = blockIdx.x * 256 + t;
    const int v = (i < N) ? cnt[i] : 0;
    part[t] = v;
    __syncthreads();
    for (int d = 1; d < 256; d <<= 1) {
        const int u = (t >= d) ? part[t - d] : 0;
        __syncthreads();
        part[t] += u;
        __syncthreads();
    }
    if (i < N) {
        const int o = bpre[blockIdx.x] + part[t] - v;
        off[i] = o;
        cursor[i] = o;
    }
    if (blockIdx.x == 0 && t == 0) off[N] = E;
}

__global__ __launch_bounds__(256) void fill_k(const int* __restrict__ ei,
                                              int* __restrict__ cursor,
                                              int* __restrict__ srcs, int E)
{
    const int gid = blockIdx.x * blockDim.x + threadIdx.x;
    const int stride = gridDim.x * blockDim.x;
    for (int e = gid; e < E; e += stride) {
        const int s = ei[e];
        const int d = ei[E + e];
        const int pos = atomicAdd(&cursor[d], 1);
        srcs[pos] = s;
    }
}

// ---------------------------------------------------------------------------
// Inline-asm 8-deep gather segment-sum (bf16 in/out) + fused column stats.
// Wave-per-node (grid-stride). Per 8-edge group: 8 volatile global_load_dword
// (SGPR row base + const lane byte-offset), one s_waitcnt vmcnt(0) with all
// results as "+v" (un-hoistable), then wave-uniform-predicated adds.
// C=128: lane l -> channels 2l,2l+1. C=64: lanes 0-31 meaningful (32-63 dup).
// ---------------------------------------------------------------------------
template <int C>
__global__ __launch_bounds__(256) void segsum_as(
    const u16* __restrict__ p, const int* __restrict__ off,
    const int* __restrict__ srcs, u16* __restrict__ out,
    float* __restrict__ sum, float* __restrict__ sumsq, int N)
{
    constexpr int LANES = (C == 128) ? 64 : 32;   // meaningful lanes
    __shared__ float redS[4][LANES][2];
    __shared__ float redQ[4][LANES][2];

    const int tid = threadIdx.x;
    const int wv = tid >> 6;
    const int l = tid & 63;
    const int ml = l & (LANES - 1);               // meaningful lane id
    const u32 loff = (u32)(ml * 4);               // byte offset within row

    const int wid = blockIdx.x * 4 + wv;
    const int nwaves = gridDim.x * 4;

    float ss0 = 0.f, ss1 = 0.f, qq0 = 0.f, qq1 = 0.f;

    for (int n = wid; n < N; n += nwaves) {
        const int lo = __builtin_amdgcn_readfirstlane(off[n]);
        const int hi = __builtin_amdgcn_readfirstlane(off[n + 1]);

        const u32 selfu = *(const u32*)&p[(size_t)n * C + ml * 2];
        float acc0 = bf2f((u16)selfu);
        float acc1 = bf2f((u16)(selfu >> 16));

        for (int e = lo; e < hi; e += 8) {
            const int m = min(hi - e, 8);         // wave-uniform
            const int last = hi - 1;
            u32 r0, r1, r2, r3, r4, r5, r6, r7;
            {
                const u16* b0 = p + (size_t)srcs[min(e + 0, last)] * C;
                const u16* b1 = p + (size_t)srcs[min(e + 1, last)] * C;
                const u16* b2 = p + (size_t)srcs[min(e + 2, last)] * C;
                const u16* b3 = p + (size_t)srcs[min(e + 3, last)] * C;
                const u16* b4 = p + (size_t)srcs[min(e + 4, last)] * C;
                const u16* b5 = p + (size_t)srcs[min(e + 5, last)] * C;
                const u16* b6 = p + (size_t)srcs[min(e + 6, last)] * C;
                const u16* b7 = p + (size_t)srcs[min(e + 7, last)] * C;
                asm volatile("global_load_dword %0, %1, %2" : "=v"(r0) : "v"(loff), "s"(b0));
                asm volatile("global_load_dword %0, %1, %2" : "=v"(r1) : "v"(loff), "s"(b1));
                asm volatile("global_load_dword %0, %1, %2" : "=v"(r2) : "v"(loff), "s"(b2));
                asm volatile("global_load_dword %0, %1, %2" : "=v"(r3) : "v"(loff), "s"(b3));
                asm volatile("global_load_dword %0, %1, %2" : "=v"(r4) : "v"(loff), "s"(b4));
                asm volatile("global_load_dword %0, %1, %2" : "=v"(r5) : "v"(loff), "s"(b5));
                asm volatile("global_load_dword %0, %1, %2" : "=v"(r6) : "v"(loff), "s"(b6));
                asm volatile("global_load_dword %0, %1, %2" : "=v"(r7) : "v"(loff), "s"(b7));
            }
            asm volatile("s_waitcnt vmcnt(0)"
                         : "+v"(r0), "+v"(r1), "+v"(r2), "+v"(r3),
                           "+v"(r4), "+v"(r5), "+v"(r6), "+v"(r7));
            // wave-uniform predicated accumulate (order = edge order)
            acc0 += bf2f((u16)r0);            acc1 += bf2f((u16)(r0 >> 16));
            if (m > 1) { acc0 += bf2f((u16)r1); acc1 += bf2f((u16)(r1 >> 16)); }
            if (m > 2) { acc0 += bf2f((u16)r2); acc1 += bf2f((u16)(r2 >> 16)); }
            if (m > 3) { acc0 += bf2f((u16)r3); acc1 += bf2f((u16)(r3 >> 16)); }
            if (m > 4) { acc0 += bf2f((u16)r4); acc1 += bf2f((u16)(r4 >> 16)); }
            if (m > 5) { acc0 += bf2f((u16)r5); acc1 += bf2f((u16)(r5 >> 16)); }
            if (m > 6) { acc0 += bf2f((u16)r6); acc1 += bf2f((u16)(r6 >> 16)); }
            if (m > 7) { acc0 += bf2f((u16)r7); acc1 += bf2f((u16)(r7 >> 16)); }
        }

        // round, write, stats (meaningful lanes only)
        if (l < LANES) {
            const u16 w0 = f2bf(acc0);
            const u16 w1 = f2bf(acc1);
            *(u32*)&out[(size_t)n * C + ml * 2] = (u32)w0 | ((u32)w1 << 16);
            const float f0 = bf2f(w0), f1 = bf2f(w1);
            ss0 += f0; qq0 += f0 * f0;
            ss1 += f1; qq1 += f1 * f1;
        }
    }

    // block reduce across 4 waves, one atomic per channel per block
    if (l < LANES) {
        redS[wv][ml][0] = ss0; redS[wv][ml][1] = ss1;
        redQ[wv][ml][0] = qq0; redQ[wv][ml][1] = qq1;
    }
    __syncthreads();
    if (wv == 0 && l < LANES) {
        float a0 = 0.f, a1 = 0.f, b0 = 0.f, b1 = 0.f;
#pragma unroll
        for (int w2 = 0; w2 < 4; w2++) {
            a0 += redS[w2][ml][0]; a1 += redS[w2][ml][1];
            b0 += redQ[w2][ml][0]; b1 += redQ[w2][ml][1];
        }
        atomAddF(&sum[2 * ml + 0], a0);
        atomAddF(&sum[2 * ml + 1], a1);
        atomAddF(&sumsq[2 * ml + 0], b0);
        atomAddF(&sumsq[2 * ml + 1], b1);
    }
}

__global__ void bnfinal_k(const float* __restrict__ sum,
                          const float* __restrict__ sumsq,
                          const float* __restrict__ g,
                          const float* __restrict__ be,
                          float* __restrict__ sc, float* __restrict__ sh,
                          int C, float invN)
{
    const int c = threadIdx.x;
    if (c < C) {
        const float m = sum[c] * invN;
        const float v = sumsq[c] * invN - m * m;
        const float r = rsqrtf(v + 1e-5f);
        const float s = g[c] * r;
        sc[c] = s;
        sh[c] = be[c] - m * s;
    }
}

extern "C" void kernel_launch(void* const* d_in, const int* in_sizes, int n_in,
                              void* d_out, int out_size, void* d_ws, size_t ws_size,
                              hipStream_t stream)
{
    const float* x   = (const float*)d_in[0];
    const int*   ei  = (const int*)d_in[1];
    const float* w1a = (const float*)d_in[2];
    // d_in[3] = b1a: cancelled by BN
    const float* g1  = (const float*)d_in[4];
    const float* be1 = (const float*)d_in[5];
    const float* w1b = (const float*)d_in[6];
    const float* b1b = (const float*)d_in[7];
    const float* w2a = (const float*)d_in[8];
    // d_in[9] = b2a: cancelled by BN
    const float* g2  = (const float*)d_in[10];
    const float* be2 = (const float*)d_in[11];
    const float* w2b = (const float*)d_in[12];
    const float* b2b = (const float*)d_in[13];
    float* out = (float*)d_out;

    const int N = in_sizes[0] / 128;   // 50000
    const int E = in_sizes[1] / 2;     // 800000

    // ---- workspace layout ----
    u16* buf1 = (u16*)d_ws;                      // N*128 bf16 : p1, then h1
    u16* buf2 = buf1 + (size_t)N * 128;          // N*128 bf16 : s1, then p2|s2
    float* stats = (float*)(buf2 + (size_t)N * 128);  // 1024 floats
    float* sum1 = stats,       *sq1 = stats + 128;
    float* sum2 = stats + 256, *sq2 = stats + 320;
    float* sc1  = stats + 384, *sh1 = stats + 512;
    float* sc2  = stats + 640, *sh2 = stats + 704;
    int* cnt    = (int*)(stats + 1024);          // N
    int* off    = cnt + N;                       // N+1
    int* cursor = off + N + 1;                   // N
    int* srcs   = cursor + N;                    // E
    int* bsum   = srcs + E;                      // 256
    int* bpre   = bsum + 256;                    // 256
    short* w1af = (short*)(bpre + 256);          // 128*128
    short* w1bf = w1af + 128 * 128;              // 128*128
    short* w2af = w1bf + 128 * 128;              // 128*64
    short* w2bf = w2af + 128 * 64;               // 64*64
    u16* p1 = buf1;
    u16* s1 = buf2;
    u16* h1 = buf1;                    // reuse: p1 dead after segsum1
    u16* p2 = buf2;                    // reuse: s1 dead after mgemm2 (N*64)
    u16* s2 = buf2 + (size_t)N * 64;   // upper half

    hipMemsetAsync(stats, 0, 1024 * sizeof(float) + (size_t)N * sizeof(int), stream);

    const int G1 = (N + 255) / 256;
    const int gb = (N + 127) / 128;
    const int gs = 2048;               // segsum_as: grid-stride, 8192 waves

    // ---- CSR build ----
    hist_k<<<1024, 256, 0, stream>>>(ei, cnt, E);
    bsum_k<<<G1, 256, 0, stream>>>(cnt, bsum, N);
    bscan_k<<<1, 256, 0, stream>>>(bsum, bpre, G1);
    offs_k<<<G1, 256, 0, stream>>>(cnt, bpre, off, cursor, N, E);
    fill_k<<<1024, 256, 0, stream>>>(ei, cursor, srcs, E);

    // ---- weight prep (one launch for all four) ----
    wprep4_k<<<22, 256, 0, stream>>>(w1a, w1b, w2a, w2b, w1af, w1bf, w2af, w2bf);

    // ---- Layer 1 ----
    mgemm<128, 128, false, false, false, false, false, true>
        <<<gb, 256, 0, stream>>>(x, w1af, nullptr, nullptr, nullptr, p1, N);
    segsum_as<128><<<gs, 256, 0, stream>>>(p1, off, srcs, s1, sum1, sq1, N);
    bnfinal_k<<<1, 128, 0, stream>>>(sum1, sq1, g1, be1, sc1, sh1, 128, 1.f / N);
    mgemm<128, 128, true, true, true, true, false, true>
        <<<gb, 256, 0, stream>>>(s1, w1bf, sc1, sh1, b1b, h1, N);

    // ---- Layer 2 (aggregate after projecting to 64ch) ----
    mgemm<128, 64, true, false, false, false, false, true>
        <<<gb, 256, 0, stream>>>(h1, w2af, nullptr, nullptr, nullptr, p2, N);
    segsum_as<64><<<gs, 256, 0, stream>>>(p2, off, srcs, s2, sum2, sq2, N);
    bnfinal_k<<<1, 64, 0, stream>>>(sum2, sq2, g2, be2, sc2, sh2, 64, 1.f / N);
    mgemm<64, 64, true, true, true, false, true, false>
        <<<gb, 256, 0, stream>>>(s2, w2bf, sc2, sh2, b2b, out, N);
}

// Round 11
// 375.846 us; speedup vs baseline: 3.7101x; 1.0629x over previous
//
#include <hip/hip_runtime.h>

// ---------------------------------------------------------------------------
// GIN 2-layer forward (bf16 features, MFMA GEMMs, CSR gather segment-sum):
//   CSR bucket edges by dst (hist -> parallel scan -> fill)
//   p1 = bf16( x @ w1a )                      [b1a cancels in BN]
//   s1 = bf16( p1[n] + gather-sum )           (fused column stats)
//   h1 = bf16( relu( relu(sc1*s1+sh1) @ w1b + b1b ) )
//   p2 = bf16( h1 @ w2a )                     [b2a cancels in BN]
//   s2 = bf16( p2[n] + gather-sum )           (fused stats)
//   out = log_softmax( relu(sc2*s2+sh2) @ w2b + b2b )  fp32, fused epilogue
// segsum_sl: XCD-SLICED gather. Channels split into 64B slices (C=128: 4,
// C=64: 2); blockIdx%8 -> slice so each XCD's L2 only sees N*64B = 3.2MB
// (fits 4MB) -> gathers become L2 hits (latency ~200cy vs ~600). Loop body
// and per-channel add order identical to the proven R4 kernel.
// ---------------------------------------------------------------------------

typedef unsigned short u16;
typedef unsigned int u32;
typedef __attribute__((ext_vector_type(8))) short short8;
typedef __attribute__((ext_vector_type(4))) short short4v;
typedef __attribute__((ext_vector_type(4))) float f32x4;

#define DEV_INLINE __device__ __forceinline__

DEV_INLINE void atomAddF(float* p, float v) { unsafeAtomicAdd(p, v); }

DEV_INLINE u16 f2bf(float f) {
    unsigned u = __float_as_uint(f);
    u += 0x7fffu + ((u >> 16) & 1u);   // round-to-nearest-even
    return (u16)(u >> 16);
}
DEV_INLINE float bf2f(u16 h) { return __uint_as_float(((unsigned)h) << 16); }

// ---------------------------------------------------------------------------
// Weight prep (all 4 weights, one launch): W[K][NOUT] fp32 -> frag-ordered
// bf16 (MFMA A-operand, swapped). unit=(ct,kc,lane): 8 bf16 for
// col=ct*16+(lane&15), k=kc*32+(lane>>4)*8+j.
// ---------------------------------------------------------------------------
__global__ __launch_bounds__(256) void wprep4_k(
    const float* __restrict__ w1a, const float* __restrict__ w1b,
    const float* __restrict__ w2a, const float* __restrict__ w2b,
    short* __restrict__ o1a, short* __restrict__ o1b,
    short* __restrict__ o2a, short* __restrict__ o2b)
{
    int b = blockIdx.x;
    const float* W; short* wf; int K, NOUT;
    if (b < 8)       { W = w1a; wf = o1a; K = 128; NOUT = 128; }
    else if (b < 16) { W = w1b; wf = o1b; K = 128; NOUT = 128; b -= 8; }
    else if (b < 20) { W = w2a; wf = o2a; K = 128; NOUT = 64;  b -= 16; }
    else             { W = w2b; wf = o2b; K = 64;  NOUT = 64;  b -= 20; }
    const int u = b * 256 + threadIdx.x;
    const int units = (NOUT / 16) * (K / 32) * 64;
    if (u >= units) return;
    const int per_ct = (K / 32) * 64;
    const int ct = u / per_ct;
    const int rem = u % per_ct;
    const int kc = rem >> 6;
    const int l = rem & 63;
    const int col = ct * 16 + (l & 15);
    const int k0 = kc * 32 + (l >> 4) * 8;
    short8 pk;
#pragma unroll
    for (int j = 0; j < 8; j++)
        pk[j] = (short)f2bf(W[(size_t)(k0 + j) * NOUT + col]);
    *(short8*)&wf[(size_t)u * 8] = pk;
}

// ---------------------------------------------------------------------------
// MFMA GEMM (swapped operands => per-lane contiguous C-writes):
//   out[M][NC] = f(A[M][KD]) @ W  (+bias) (+relu | +row log_softmax)
// A is fp32 or bf16; out is bf16 or fp32. BM=128 rows, 256 threads (4 waves).
// ---------------------------------------------------------------------------
template <int KD, int NC, bool ABF16, bool BNIN, bool BIAS, bool RELUOUT,
          bool LOGSM, bool OBF16>
__global__ __launch_bounds__(256) void mgemm(
    const void* __restrict__ Ap, const short* __restrict__ Wf,
    const float* __restrict__ sc, const float* __restrict__ sh,
    const float* __restrict__ bias, void* __restrict__ outp, int M)
{
    constexpr int BM = 128;
    constexpr int KC = KD / 32;   // 32-wide k chunks
    constexpr int CT = NC / 16;   // 16-wide col tiles
    __shared__ short Asl[BM * KD];
    __shared__ short Bsl[NC * KD];

    const int t = threadIdx.x;
    const int l = t & 63;
    const int w = t >> 6;

    // ---- stage B: frag-ordered weights, linear copy ----
    {
        const float4* src = (const float4*)Wf;
        float4* dst = (float4*)Bsl;
        constexpr int NU = NC * KD / 8;
#pragma unroll
        for (int u = t; u < NU; u += 256) dst[u] = src[u];
    }
    // ---- stage A: 2 threads per row -> (BN+ReLU) -> bf16 frags ----
    {
        const int r = t >> 1;
        const int half = t & 1;
        const int grow = blockIdx.x * BM + r;
        const int rt = r >> 4;
        constexpr int KH = KD / 2;
        u16 hv[KH];
        if (grow < M) {
            if constexpr (ABF16) {
                const u16* ap = (const u16*)Ap + (size_t)grow * KD + half * KH;
#pragma unroll
                for (int i = 0; i < KH / 8; i++)
                    *(short8*)&hv[i * 8] = ((const short8*)ap)[i];
                if constexpr (BNIN) {
#pragma unroll
                    for (int i = 0; i < KH; i++) {
                        const int k = half * KH + i;
                        hv[i] = f2bf(fmaxf(0.f, bf2f(hv[i]) * sc[k] + sh[k]));
                    }
                }
            } else {
                const float* ap = (const float*)Ap + (size_t)grow * KD + half * KH;
#pragma unroll
                for (int i = 0; i < KH / 4; i++) {
                    const float4 v = ((const float4*)ap)[i];
                    float f0 = v.x, f1 = v.y, f2 = v.z, f3 = v.w;
                    if constexpr (BNIN) {
                        const int k = half * KH + i * 4;
                        f0 = fmaxf(0.f, f0 * sc[k + 0] + sh[k + 0]);
                        f1 = fmaxf(0.f, f1 * sc[k + 1] + sh[k + 1]);
                        f2 = fmaxf(0.f, f2 * sc[k + 2] + sh[k + 2]);
                        f3 = fmaxf(0.f, f3 * sc[k + 3] + sh[k + 3]);
                    }
                    hv[i * 4 + 0] = f2bf(f0); hv[i * 4 + 1] = f2bf(f1);
                    hv[i * 4 + 2] = f2bf(f2); hv[i * 4 + 3] = f2bf(f3);
                }
            }
        } else {
#pragma unroll
            for (int i = 0; i < KH; i++) hv[i] = 0;
        }
#pragma unroll
        for (int g = 0; g < KH / 8; g++) {
            const int k0 = half * KH + g * 8;
            const int kc = k0 >> 5;
            const int lane = (r & 15) + ((k0 >> 3) & 3) * 16;
            *(short8*)&Asl[((rt * KC + kc) * 64 + lane) * 8] =
                *(short8*)&hv[g * 8];
        }
    }
    __syncthreads();

    // ---- MFMA: wave w owns row-tiles {2w, 2w+1} x all col-tiles ----
    const int rt0 = w * 2;
    f32x4 acc[2][CT];
#pragma unroll
    for (int i = 0; i < 2; i++)
#pragma unroll
        for (int c = 0; c < CT; c++) acc[i][c] = (f32x4){0.f, 0.f, 0.f, 0.f};

#pragma unroll
    for (int kc = 0; kc < KC; kc++) {
        const short8 x0 = *(const short8*)&Asl[((rt0 * KC + kc) * 64 + l) * 8];
        const short8 x1 = *(const short8*)&Asl[(((rt0 + 1) * KC + kc) * 64 + l) * 8];
#pragma unroll
        for (int ct = 0; ct < CT; ct++) {
            const short8 wb = *(const short8*)&Bsl[((ct * KC + kc) * 64 + l) * 8];
            acc[0][ct] = __builtin_amdgcn_mfma_f32_16x16x32_bf16(wb, x0, acc[0][ct], 0, 0, 0);
            acc[1][ct] = __builtin_amdgcn_mfma_f32_16x16x32_bf16(wb, x1, acc[1][ct], 0, 0, 0);
        }
    }

    // ---- epilogue: lane l holds row (l&15), cols (l>>4)*4+{0..3} of tile ----
    const int cbase = (l >> 4) * 4;
#pragma unroll
    for (int rr = 0; rr < 2; rr++) {
        const int grow = blockIdx.x * BM + (rt0 + rr) * 16 + (l & 15);
        if constexpr (!LOGSM) {
            if (grow < M) {
#pragma unroll
                for (int ct = 0; ct < CT; ct++) {
                    f32x4 o = acc[rr][ct];
                    if constexpr (BIAS) {
                        const float4 bv = *(const float4*)&bias[ct * 16 + cbase];
                        o[0] += bv.x; o[1] += bv.y; o[2] += bv.z; o[3] += bv.w;
                    }
                    if constexpr (RELUOUT) {
#pragma unroll
                        for (int j = 0; j < 4; j++) o[j] = fmaxf(o[j], 0.f);
                    }
                    if constexpr (OBF16) {
                        short4v o16;
#pragma unroll
                        for (int j = 0; j < 4; j++) o16[j] = (short)f2bf(o[j]);
                        *(short4v*)&((u16*)outp)[(size_t)grow * NC + ct * 16 + cbase] = o16;
                    } else {
                        *(f32x4*)&((float*)outp)[(size_t)grow * NC + ct * 16 + cbase] = o;
                    }
                }
            }
        } else {
            // fused row log_softmax (row spread across lanes l, l^16, l^32, l^48)
            float v[CT * 4];
#pragma unroll
            for (int ct = 0; ct < CT; ct++) {
                const float4 bv = *(const float4*)&bias[ct * 16 + cbase];
                v[ct * 4 + 0] = acc[rr][ct][0] + bv.x;
                v[ct * 4 + 1] = acc[rr][ct][1] + bv.y;
                v[ct * 4 + 2] = acc[rr][ct][2] + bv.z;
                v[ct * 4 + 3] = acc[rr][ct][3] + bv.w;
            }
            float m = v[0];
#pragma unroll
            for (int j = 1; j < CT * 4; j++) m = fmaxf(m, v[j]);
            m = fmaxf(m, __shfl_xor(m, 16));
            m = fmaxf(m, __shfl_xor(m, 32));
            float s = 0.f;
#pragma unroll
            for (int j = 0; j < CT * 4; j++) s += __expf(v[j] - m);
            s += __shfl_xor(s, 16);
            s += __shfl_xor(s, 32);
            const float lg = m + __logf(s);
            if (grow < M) {
#pragma unroll
                for (int ct = 0; ct < CT; ct++) {
                    f32x4 o;
#pragma unroll
                    for (int j = 0; j < 4; j++) o[j] = v[ct * 4 + j] - lg;
                    *(f32x4*)&((float*)outp)[(size_t)grow * NC + ct * 16 + cbase] = o;
                }
            }
        }
    }
}

// ---------------------------------------------------------------------------
// CSR build: histogram, 3-kernel parallel exclusive scan, bucket fill.
// ---------------------------------------------------------------------------
__global__ __launch_bounds__(256) void hist_k(const int* __restrict__ ei,
                                              int* __restrict__ cnt, int E)
{
    const int gid = blockIdx.x * blockDim.x + threadIdx.x;
    const int stride = gridDim.x * blockDim.x;
    for (int e = gid; e < E; e += stride) atomicAdd(&cnt[ei[E + e]], 1);
}

__global__ __launch_bounds__(256) void bsum_k(const int* __restrict__ cnt,
                                              int* __restrict__ bsum, int N)
{
    __shared__ int ws[4];
    const int i = blockIdx.x * 256 + threadIdx.x;
    int v = (i < N) ? cnt[i] : 0;
    for (int d = 32; d; d >>= 1) v += __shfl_xor(v, d, 64);
    if ((threadIdx.x & 63) == 0) ws[threadIdx.x >> 6] = v;
    __syncthreads();
    if (threadIdx.x == 0) bsum[blockIdx.x] = ws[0] + ws[1] + ws[2] + ws[3];
}

// single block; G1 <= 256
__global__ __launch_bounds__(256) void bscan_k(const int* __restrict__ bsum,
                                               int* __restrict__ bpre, int G1)
{
    __shared__ int part[256];
    const int t = threadIdx.x;
    const int v = (t < G1) ? bsum[t] : 0;
    part[t] = v;
    __syncthreads();
    for (int d = 1; d < 256; d <<= 1) {
        const int u = (t >= d) ? part[t - d] : 0;
        __syncthreads();
        part[t] += u;
        __syncthreads();
    }
    bpre[t] = part[t] - v;   // exclusive
}

__global__ __launch_bounds__(256) void offs_k(const int* __restrict__ cnt,
                                              const int* __restrict__ bpre,
                                              int* __restrict__ off,
                                              int* __restrict__ cursor,
                                              int N, int E)
{
    __shared__ int part[256];
    const int t = threadIdx.x;
    const int i = blockIdx.x * 256 + t;
    const int v = (i < N) ? cnt[i] : 0;
    part[t] = v;
    __syncthreads();
    for (int d = 1; d < 256; d <<= 1) {
        const int u = (t >= d) ? part[t - d] : 0;
        __syncthreads();
        part[t] += u;
        __syncthreads();
    }
    if (i < N) {
        const int o = bpre[blockIdx.x] + part[t] - v;
        off[i] = o;
        cursor[i] = o;
    }
    if (blockIdx.x == 0 && t == 0) off[N] = E;
}

__global__ __launch_bounds__(256) void fill_k(const int* __restrict__ ei,
                                              int* __restrict__ cursor,
                                              int* __restrict__ srcs, int E)
{
    const int gid = blockIdx.x * blockDim.x + threadIdx.x;
    const int stride = gridDim.x * blockDim.x;
    for (int e = gid; e < E; e += stride) {
        const int s = ei[e];
        const int d = ei[E + e];
        const int pos = atomicAdd(&cursor[d], 1);
        srcs[pos] = s;
    }
}

// ---------------------------------------------------------------------------
// XCD-sliced gather segment-sum (bf16 in/out) + fused column stats.
// Channel slices of 64B (32ch): C=128 -> 4 slices, C=64 -> 2 slices.
// blockIdx%8 selects the slice so each XCD's L2 sees only N*64B = 3.2MB.
// Within a block: R4's proven structure -- 4 waves x 8 nodes, wave-per-node,
// dword gathers (lane&15 -> 2 channels; lanes 16-63 duplicate = same sector),
// unroll-8 with index prefetch. Per-channel add order == R4 (bit-identical).
// ---------------------------------------------------------------------------
template <int C>
__global__ __launch_bounds__(256) void segsum_sl(
    const u16* __restrict__ p, const int* __restrict__ off,
    const int* __restrict__ srcs, u16* __restrict__ out,
    float* __restrict__ sum, float* __restrict__ sumsq, int N)
{
    constexpr int BLKN = 8;                 // nodes per wave
    __shared__ float red[4][16][4];

    const int wv = threadIdx.x >> 6;
    const int l  = threadIdx.x & 63;
    const int sub = l & 15;

    const int nchunks = (N + 31) / 32;
    const int x = blockIdx.x & 7;           // XCD id under round-robin
    const int g = blockIdx.x >> 3;
    int slice, chunk;
    if constexpr (C == 128) { slice = x & 3; chunk = g * 2 + (x >> 2); }
    else                    { slice = x & 1; chunk = g * 4 + (x >> 1); }
    const int soff = slice * 32;            // channel offset of this slice

    float ss0 = 0.f, ss1 = 0.f, qq0 = 0.f, qq1 = 0.f;

    if (chunk < nchunks) {
        const int base = chunk * 32;
        for (int i = 0; i < BLKN; i++) {
            const int n = base + i * 4 + wv;
            if (n < N) {
                const int lo = __builtin_amdgcn_readfirstlane(off[n]);
                const int hi = __builtin_amdgcn_readfirstlane(off[n + 1]);
                const u32 u0 = *(const u32*)&p[(size_t)n * C + soff + sub * 2];
                float acc0 = bf2f((u16)u0);
                float acc1 = bf2f((u16)(u0 >> 16));
                if (lo < hi) {
                    const int last = hi - 1;
                    int idx[8];
#pragma unroll
                    for (int j = 0; j < 8; j++) idx[j] = srcs[min(lo + j, last)];
                    for (int e = lo; e < hi; e += 8) {
                        int nx[8];
#pragma unroll
                        for (int j = 0; j < 8; j++)
                            nx[j] = srcs[min(e + 8 + j, last)];   // prefetch
#pragma unroll
                        for (int j = 0; j < 8; j++) {
                            const bool live = (e + j) < hi;
                            const u32 u = *(const u32*)&p[(size_t)idx[j] * C + soff + sub * 2];
                            const float v0 = bf2f((u16)u);
                            const float v1 = bf2f((u16)(u >> 16));
                            acc0 += live ? v0 : 0.f;
                            acc1 += live ? v1 : 0.f;
                        }
#pragma unroll
                        for (int j = 0; j < 8; j++) idx[j] = nx[j];
                    }
                }
                const u16 r0 = f2bf(acc0);
                const u16 r1 = f2bf(acc1);
                if (l < 16)
                    *(u32*)&out[(size_t)n * C + soff + sub * 2] =
                        (u32)r0 | ((u32)r1 << 16);
                const float f0 = bf2f(r0), f1 = bf2f(r1);
                ss0 += f0; qq0 += f0 * f0;
                ss1 += f1; qq1 += f1 * f1;
            }
        }
    }

    // cross-wave reduce (lanes 0-15 carry the data), one atomic per channel
    if (l < 16) {
        red[wv][sub][0] = ss0; red[wv][sub][1] = ss1;
        red[wv][sub][2] = qq0; red[wv][sub][3] = qq1;
    }
    __syncthreads();
    if (wv == 0 && l < 16 && chunk < nchunks) {
        float a0 = 0.f, a1 = 0.f, b0 = 0.f, b1 = 0.f;
#pragma unroll
        for (int w2 = 0; w2 < 4; w2++) {
            a0 += red[w2][sub][0]; a1 += red[w2][sub][1];
            b0 += red[w2][sub][2]; b1 += red[w2][sub][3];
        }
        const int ch = soff + sub * 2;
        atomAddF(&sum[ch], a0);
        atomAddF(&sum[ch + 1], a1);
        atomAddF(&sumsq[ch], b0);
        atomAddF(&sumsq[ch + 1], b1);
    }
}

__global__ void bnfinal_k(const float* __restrict__ sum,
                          const float* __restrict__ sumsq,
                          const float* __restrict__ g,
                          const float* __restrict__ be,
                          float* __restrict__ sc, float* __restrict__ sh,
                          int C, float invN)
{
    const int c = threadIdx.x;
    if (c < C) {
        const float m = sum[c] * invN;
        const float v = sumsq[c] * invN - m * m;
        const float r = rsqrtf(v + 1e-5f);
        const float s = g[c] * r;
        sc[c] = s;
        sh[c] = be[c] - m * s;
    }
}

extern "C" void kernel_launch(void* const* d_in, const int* in_sizes, int n_in,
                              void* d_out, int out_size, void* d_ws, size_t ws_size,
                              hipStream_t stream)
{
    const float* x   = (const float*)d_in[0];
    const int*   ei  = (const int*)d_in[1];
    const float* w1a = (const float*)d_in[2];
    // d_in[3] = b1a: cancelled by BN
    const float* g1  = (const float*)d_in[4];
    const float* be1 = (const float*)d_in[5];
    const float* w1b = (const float*)d_in[6];
    const float* b1b = (const float*)d_in[7];
    const float* w2a = (const float*)d_in[8];
    // d_in[9] = b2a: cancelled by BN
    const float* g2  = (const float*)d_in[10];
    const float* be2 = (const float*)d_in[11];
    const float* w2b = (const float*)d_in[12];
    const float* b2b = (const float*)d_in[13];
    float* out = (float*)d_out;

    const int N = in_sizes[0] / 128;   // 50000
    const int E = in_sizes[1] / 2;     // 800000

    // ---- workspace layout ----
    u16* buf1 = (u16*)d_ws;                      // N*128 bf16 : p1, then h1
    u16* buf2 = buf1 + (size_t)N * 128;          // N*128 bf16 : s1, then p2|s2
    float* stats = (float*)(buf2 + (size_t)N * 128);  // 1024 floats
    float* sum1 = stats,       *sq1 = stats + 128;
    float* sum2 = stats + 256, *sq2 = stats + 320;
    float* sc1  = stats + 384, *sh1 = stats + 512;
    float* sc2  = stats + 640, *sh2 = stats + 704;
    int* cnt    = (int*)(stats + 1024);          // N
    int* off    = cnt + N;                       // N+1
    int* cursor = off + N + 1;                   // N
    int* srcs   = cursor + N;                    // E
    int* bsum   = srcs + E;                      // 256
    int* bpre   = bsum + 256;                    // 256
    short* w1af = (short*)(bpre + 256);          // 128*128
    short* w1bf = w1af + 128 * 128;              // 128*128
    short* w2af = w1bf + 128 * 128;              // 128*64
    short* w2bf = w2af + 128 * 64;               // 64*64
    u16* p1 = buf1;
    u16* s1 = buf2;
    u16* h1 = buf1;                    // reuse: p1 dead after segsum1
    u16* p2 = buf2;                    // reuse: s1 dead after mgemm2 (N*64)
    u16* s2 = buf2 + (size_t)N * 64;   // upper half

    hipMemsetAsync(stats, 0, 1024 * sizeof(float) + (size_t)N * sizeof(int), stream);

    const int G1 = (N + 255) / 256;
    const int gb = (N + 127) / 128;
    const int nchunks = (N + 31) / 32;
    const int gs1 = 8 * ((nchunks + 1) / 2);   // C=128: 4 slices x 2 chunk-lanes
    const int gs2 = 8 * ((nchunks + 3) / 4);   // C=64 : 2 slices x 4 chunk-lanes

    // ---- CSR build ----
    hist_k<<<1024, 256, 0, stream>>>(ei, cnt, E);
    bsum_k<<<G1, 256, 0, stream>>>(cnt, bsum, N);
    bscan_k<<<1, 256, 0, stream>>>(bsum, bpre, G1);
    offs_k<<<G1, 256, 0, stream>>>(cnt, bpre, off, cursor, N, E);
    fill_k<<<1024, 256, 0, stream>>>(ei, cursor, srcs, E);

    // ---- weight prep (one launch for all four) ----
    wprep4_k<<<22, 256, 0, stream>>>(w1a, w1b, w2a, w2b, w1af, w1bf, w2af, w2bf);

    // ---- Layer 1 ----
    mgemm<128, 128, false, false, false, false, false, true>
        <<<gb, 256, 0, stream>>>(x, w1af, nullptr, nullptr, nullptr, p1, N);
    segsum_sl<128><<<gs1, 256, 0, stream>>>(p1, off, srcs, s1, sum1, sq1, N);
    bnfinal_k<<<1, 128, 0, stream>>>(sum1, sq1, g1, be1, sc1, sh1, 128, 1.f / N);
    mgemm<128, 128, true, true, true, true, false, true>
        <<<gb, 256, 0, stream>>>(s1, w1bf, sc1, sh1, b1b, h1, N);

    // ---- Layer 2 (aggregate after projecting to 64ch) ----
    mgemm<128, 64, true, false, false, false, false, true>
        <<<gb, 256, 0, stream>>>(h1, w2af, nullptr, nullptr, nullptr, p2, N);
    segsum_sl<64><<<gs2, 256, 0, stream>>>(p2, off, srcs, s2, sum2, sq2, N);
    bnfinal_k<<<1, 64, 0, stream>>>(sum2, sq2, g2, be2, sc2, sh2, 64, 1.f / N);
    mgemm<64, 64, true, true, true, false, true, false>
        <<<gb, 256, 0, stream>>>(s2, w2bf, sc2, sh2, b2b, out, N);
}

// Round 12
// 302.085 us; speedup vs baseline: 4.6160x; 1.2442x over previous
//
#include <hip/hip_runtime.h>

// ---------------------------------------------------------------------------
// GIN 2-layer forward (bf16 features, MFMA GEMMs, CSR gather segment-sum):
//   CSR bucket edges by dst (hist -> parallel scan -> fill)
//   p1 = bf16( x @ w1a )                      [b1a cancels in BN]
//   s1 = bf16( p1[n] + gather-sum )           (fused column stats)
//   h1 = bf16( relu( relu(BN(s1)) @ w1b + b1b ) )   [BN affine computed
//   p2 = bf16( h1 @ w2a )                            in-kernel from stats]
//   s2 = bf16( p2[n] + gather-sum )
//   out = log_softmax( relu(BN(s2)) @ w2b + b2b )  fp32, fused epilogue
// R11: segsum = R5's measured-best (96/55us). mgemm BM 128->64 for 3-5
// blocks/CU occupancy; bnfinal fused into BNIN gemms (2 launches removed).
// ---------------------------------------------------------------------------

typedef unsigned short u16;
typedef unsigned int u32;
typedef __attribute__((ext_vector_type(8))) short short8;
typedef __attribute__((ext_vector_type(4))) short short4v;
typedef __attribute__((ext_vector_type(4))) float f32x4;

#define DEV_INLINE __device__ __forceinline__

DEV_INLINE void atomAddF(float* p, float v) { unsafeAtomicAdd(p, v); }

DEV_INLINE u16 f2bf(float f) {
    unsigned u = __float_as_uint(f);
    u += 0x7fffu + ((u >> 16) & 1u);   // round-to-nearest-even
    return (u16)(u >> 16);
}
DEV_INLINE float bf2f(u16 h) { return __uint_as_float(((unsigned)h) << 16); }

// ---------------------------------------------------------------------------
// Weight prep (all 4 weights, one launch): W[K][NOUT] fp32 -> frag-ordered
// bf16 (MFMA A-operand, swapped). unit=(ct,kc,lane): 8 bf16 for
// col=ct*16+(lane&15), k=kc*32+(lane>>4)*8+j.
// ---------------------------------------------------------------------------
__global__ __launch_bounds__(256) void wprep4_k(
    const float* __restrict__ w1a, const float* __restrict__ w1b,
    const float* __restrict__ w2a, const float* __restrict__ w2b,
    short* __restrict__ o1a, short* __restrict__ o1b,
    short* __restrict__ o2a, short* __restrict__ o2b)
{
    int b = blockIdx.x;
    const float* W; short* wf; int K, NOUT;
    if (b < 8)       { W = w1a; wf = o1a; K = 128; NOUT = 128; }
    else if (b < 16) { W = w1b; wf = o1b; K = 128; NOUT = 128; b -= 8; }
    else if (b < 20) { W = w2a; wf = o2a; K = 128; NOUT = 64;  b -= 16; }
    else             { W = w2b; wf = o2b; K = 64;  NOUT = 64;  b -= 20; }
    const int u = b * 256 + threadIdx.x;
    const int units = (NOUT / 16) * (K / 32) * 64;
    if (u >= units) return;
    const int per_ct = (K / 32) * 64;
    const int ct = u / per_ct;
    const int rem = u % per_ct;
    const int kc = rem >> 6;
    const int l = rem & 63;
    const int col = ct * 16 + (l & 15);
    const int k0 = kc * 32 + (l >> 4) * 8;
    short8 pk;
#pragma unroll
    for (int j = 0; j < 8; j++)
        pk[j] = (short)f2bf(W[(size_t)(k0 + j) * NOUT + col]);
    *(short8*)&wf[(size_t)u * 8] = pk;
}

// ---------------------------------------------------------------------------
// MFMA GEMM, BM=64 rows/block (3-5 blocks/CU): out[M][NC] = f(A[M][KD]) @ W
// f = identity or BN+ReLU with sc/sh computed IN-KERNEL from sum/sumsq.
// 256 threads = 4 waves; wave w owns row-tile w; CT col-tiles each.
// ---------------------------------------------------------------------------
template <int KD, int NC, bool ABF16, bool BNIN, bool BIAS, bool RELUOUT,
          bool LOGSM, bool OBF16>
__global__ __launch_bounds__(256) void mgemm(
    const void* __restrict__ Ap, const short* __restrict__ Wf,
    const float* __restrict__ sum, const float* __restrict__ sumsq,
    const float* __restrict__ g, const float* __restrict__ be, float invN,
    const float* __restrict__ bias, void* __restrict__ outp, int M)
{
    constexpr int BM = 64;
    constexpr int KC = KD / 32;     // 32-wide k chunks
    constexpr int CT = NC / 16;     // 16-wide col tiles
    constexpr int KQ = KD / 4;      // elements per staging thread
    __shared__ short Asl[BM * KD];
    __shared__ short Bsl[NC * KD];
    __shared__ float scb[BNIN ? KD : 1];
    __shared__ float shb[BNIN ? KD : 1];

    const int t = threadIdx.x;
    const int l = t & 63;
    const int w = t >> 6;

    // ---- fused BN-affine from stats (replaces bnfinal kernel) ----
    if constexpr (BNIN) {
        if (t < KD) {
            const float m = sum[t] * invN;
            const float v = sumsq[t] * invN - m * m;
            const float r = rsqrtf(v + 1e-5f);
            const float s = g[t] * r;
            scb[t] = s;
            shb[t] = be[t] - m * s;
        }
        __syncthreads();
    }

    // ---- stage B: frag-ordered weights, linear copy ----
    {
        const float4* src = (const float4*)Wf;
        float4* dst = (float4*)Bsl;
        constexpr int NU = NC * KD / 8;
#pragma unroll
        for (int u = t; u < NU; u += 256) dst[u] = src[u];
    }
    // ---- stage A: 4 threads per row, KQ elems each -> (BN+ReLU) -> frags ----
    {
        const int r = t >> 2;
        const int q = t & 3;
        const int grow = blockIdx.x * BM + r;
        const int rt = r >> 4;
        u16 hv[KQ];
        if (grow < M) {
            if constexpr (ABF16) {
                const u16* ap = (const u16*)Ap + (size_t)grow * KD + q * KQ;
#pragma unroll
                for (int i = 0; i < KQ / 8; i++)
                    *(short8*)&hv[i * 8] = ((const short8*)ap)[i];
                if constexpr (BNIN) {
#pragma unroll
                    for (int i = 0; i < KQ; i++) {
                        const int k = q * KQ + i;
                        hv[i] = f2bf(fmaxf(0.f, bf2f(hv[i]) * scb[k] + shb[k]));
                    }
                }
            } else {
                const float* ap = (const float*)Ap + (size_t)grow * KD + q * KQ;
#pragma unroll
                for (int i = 0; i < KQ / 4; i++) {
                    const float4 v = ((const float4*)ap)[i];
                    float f0 = v.x, f1 = v.y, f2 = v.z, f3 = v.w;
                    if constexpr (BNIN) {
                        const int k = q * KQ + i * 4;
                        f0 = fmaxf(0.f, f0 * scb[k + 0] + shb[k + 0]);
                        f1 = fmaxf(0.f, f1 * scb[k + 1] + shb[k + 1]);
                        f2 = fmaxf(0.f, f2 * scb[k + 2] + shb[k + 2]);
                        f3 = fmaxf(0.f, f3 * scb[k + 3] + shb[k + 3]);
                    }
                    hv[i * 4 + 0] = f2bf(f0); hv[i * 4 + 1] = f2bf(f1);
                    hv[i * 4 + 2] = f2bf(f2); hv[i * 4 + 3] = f2bf(f3);
                }
            }
        } else {
#pragma unroll
            for (int i = 0; i < KQ; i++) hv[i] = 0;
        }
#pragma unroll
        for (int gg = 0; gg < KQ / 8; gg++) {
            const int k0 = q * KQ + gg * 8;
            const int kc = k0 >> 5;
            const int lane = (r & 15) + ((k0 >> 3) & 3) * 16;
            *(short8*)&Asl[((rt * KC + kc) * 64 + lane) * 8] =
                *(short8*)&hv[gg * 8];
        }
    }
    __syncthreads();

    // ---- MFMA: wave w owns row-tile w x all col-tiles ----
    f32x4 acc[CT];
#pragma unroll
    for (int c = 0; c < CT; c++) acc[c] = (f32x4){0.f, 0.f, 0.f, 0.f};

#pragma unroll
    for (int kc = 0; kc < KC; kc++) {
        const short8 x0 = *(const short8*)&Asl[((w * KC + kc) * 64 + l) * 8];
#pragma unroll
        for (int ct = 0; ct < CT; ct++) {
            const short8 wb = *(const short8*)&Bsl[((ct * KC + kc) * 64 + l) * 8];
            acc[ct] = __builtin_amdgcn_mfma_f32_16x16x32_bf16(wb, x0, acc[ct], 0, 0, 0);
        }
    }

    // ---- epilogue: lane l holds row (l&15), cols (l>>4)*4+{0..3} of tile ----
    const int cbase = (l >> 4) * 4;
    const int grow = blockIdx.x * BM + w * 16 + (l & 15);
    if constexpr (!LOGSM) {
        if (grow < M) {
#pragma unroll
            for (int ct = 0; ct < CT; ct++) {
                f32x4 o = acc[ct];
                if constexpr (BIAS) {
                    const float4 bv = *(const float4*)&bias[ct * 16 + cbase];
                    o[0] += bv.x; o[1] += bv.y; o[2] += bv.z; o[3] += bv.w;
                }
                if constexpr (RELUOUT) {
#pragma unroll
                    for (int j = 0; j < 4; j++) o[j] = fmaxf(o[j], 0.f);
                }
                if constexpr (OBF16) {
                    short4v o16;
#pragma unroll
                    for (int j = 0; j < 4; j++) o16[j] = (short)f2bf(o[j]);
                    *(short4v*)&((u16*)outp)[(size_t)grow * NC + ct * 16 + cbase] = o16;
                } else {
                    *(f32x4*)&((float*)outp)[(size_t)grow * NC + ct * 16 + cbase] = o;
                }
            }
        }
    } else {
        // fused row log_softmax (row spread across lanes l, l^16, l^32, l^48)
        float v[CT * 4];
#pragma unroll
        for (int ct = 0; ct < CT; ct++) {
            const float4 bv = *(const float4*)&bias[ct * 16 + cbase];
            v[ct * 4 + 0] = acc[ct][0] + bv.x;
            v[ct * 4 + 1] = acc[ct][1] + bv.y;
            v[ct * 4 + 2] = acc[ct][2] + bv.z;
            v[ct * 4 + 3] = acc[ct][3] + bv.w;
        }
        float m = v[0];
#pragma unroll
        for (int j = 1; j < CT * 4; j++) m = fmaxf(m, v[j]);
        m = fmaxf(m, __shfl_xor(m, 16));
        m = fmaxf(m, __shfl_xor(m, 32));
        float s = 0.f;
#pragma unroll
        for (int j = 0; j < CT * 4; j++) s += __expf(v[j] - m);
        s += __shfl_xor(s, 16);
        s += __shfl_xor(s, 32);
        const float lg = m + __logf(s);
        if (grow < M) {
#pragma unroll
            for (int ct = 0; ct < CT; ct++) {
                f32x4 o;
#pragma unroll
                for (int j = 0; j < 4; j++) o[j] = v[ct * 4 + j] - lg;
                *(f32x4*)&((float*)outp)[(size_t)grow * NC + ct * 16 + cbase] = o;
            }
        }
    }
}

// ---------------------------------------------------------------------------
// CSR build: histogram, 3-kernel parallel exclusive scan, bucket fill.
// ---------------------------------------------------------------------------
__global__ __launch_bounds__(256) void hist_k(const int* __restrict__ ei,
                                              int* __restrict__ cnt, int E)
{
    const int gid = blockIdx.x * blockDim.x + threadIdx.x;
    const int stride = gridDim.x * blockDim.x;
    for (int e = gid; e < E; e += stride) atomicAdd(&cnt[ei[E + e]], 1);
}

__global__ __launch_bounds__(256) void bsum_k(const int* __restrict__ cnt,
                                              int* __restrict__ bsum, int N)
{
    __shared__ int ws[4];
    const int i = blockIdx.x * 256 + threadIdx.x;
    int v = (i < N) ? cnt[i] : 0;
    for (int d = 32; d; d >>= 1) v += __shfl_xor(v, d, 64);
    if ((threadIdx.x & 63) == 0) ws[threadIdx.x >> 6] = v;
    __syncthreads();
    if (threadIdx.x == 0) bsum[blockIdx.x] = ws[0] + ws[1] + ws[2] + ws[3];
}

// single block; G1 <= 256
__global__ __launch_bounds__(256) void bscan_k(const int* __restrict__ bsum,
                                               int* __restrict__ bpre, int G1)
{
    __shared__ int part[256];
    const int t = threadIdx.x;
    const int v = (t < G1) ? bsum[t] : 0;
    part[t] = v;
    __syncthreads();
    for (int d = 1; d < 256; d <<= 1) {
        const int u = (t >= d) ? part[t - d] : 0;
        __syncthreads();
        part[t] += u;
        __syncthreads();
    }
    bpre[t] = part[t] - v;   // exclusive
}

__global__ __launch_bounds__(256) void offs_k(const int* __restrict__ cnt,
                                              const int* __restrict__ bpre,
                                              int* __restrict__ off,
                                              int* __restrict__ cursor,
                                              int N, int E)
{
    __shared__ int part[256];
    const int t = threadIdx.x;
    const int i = blockIdx.x * 256 + t;
    const int v = (i < N) ? cnt[i] : 0;
    part[t] = v;
    __syncthreads();
    for (int d = 1; d < 256; d <<= 1) {
        const int u = (t >= d) ? part[t - d] : 0;
        __syncthreads();
        part[t] += u;
        __syncthreads();
    }
    if (i < N) {
        const int o = bpre[blockIdx.x] + part[t] - v;
        off[i] = o;
        cursor[i] = o;
    }
    if (blockIdx.x == 0 && t == 0) off[N] = E;
}

__global__ __launch_bounds__(256) void fill_k(const int* __restrict__ ei,
                                              int* __restrict__ cursor,
                                              int* __restrict__ srcs, int E)
{
    const int gid = blockIdx.x * blockDim.x + threadIdx.x;
    const int stride = gridDim.x * blockDim.x;
    for (int e = gid; e < E; e += stride) {
        const int s = ei[e];
        const int d = ei[E + e];
        const int pos = atomicAdd(&cursor[d], 1);
        srcs[pos] = s;
    }
}

// ---------------------------------------------------------------------------
// Gather segment-sum (bf16 in/out) + fused column stats.  [R5 measured-best]
// Wave-per-node, dword gathers, unroll-8 + index prefetch.
// ---------------------------------------------------------------------------
template <int C>
__global__ __launch_bounds__(256) void segsum_bf(
    const u16* __restrict__ p, const int* __restrict__ off,
    const int* __restrict__ srcs, u16* __restrict__ out,
    float* __restrict__ sum, float* __restrict__ sumsq, int N)
{
    constexpr int BLKN = 8;            // nodes per wave
    constexpr int VPL = C / 64;        // channels per lane (2 or 1)
    __shared__ float red[4][64][2 * VPL];

    const int wv = threadIdx.x >> 6;
    const int l  = threadIdx.x & 63;
    const int base = blockIdx.x * 4 * BLKN;

    float ss[VPL], qq[VPL];
#pragma unroll
    for (int v = 0; v < VPL; v++) { ss[v] = 0.f; qq[v] = 0.f; }

    for (int i = 0; i < BLKN; i++) {
        const int n = base + i * 4 + wv;
        if (n < N) {
            const int lo = __builtin_amdgcn_readfirstlane(off[n]);
            const int hi = __builtin_amdgcn_readfirstlane(off[n + 1]);
            float acc[VPL];
            if constexpr (VPL == 2) {
                const u32 u = *(const u32*)&p[(size_t)n * C + 2 * l];
                acc[0] = bf2f((u16)u);
                acc[1] = bf2f((u16)(u >> 16));
            } else {
                acc[0] = bf2f(p[(size_t)n * C + l]);
            }
            const int cnt = hi - lo;
            if (cnt > 0) {
                const int last = hi - 1;
                int idx[8];
#pragma unroll
                for (int j = 0; j < 8; j++) idx[j] = srcs[min(lo + j, last)];
                for (int e = lo; e < hi; e += 8) {
                    int nx[8];
#pragma unroll
                    for (int j = 0; j < 8; j++)
                        nx[j] = srcs[min(e + 8 + j, last)];   // prefetch next
#pragma unroll
                    for (int j = 0; j < 8; j++) {
                        const bool live = (e + j) < hi;
                        if constexpr (VPL == 2) {
                            const u32 u = *(const u32*)&p[(size_t)idx[j] * C + 2 * l];
                            const float v0 = bf2f((u16)u);
                            const float v1 = bf2f((u16)(u >> 16));
                            acc[0] += live ? v0 : 0.f;
                            acc[1] += live ? v1 : 0.f;
                        } else {
                            const float v = bf2f(p[(size_t)idx[j] * C + l]);
                            acc[0] += live ? v : 0.f;
                        }
                    }
#pragma unroll
                    for (int j = 0; j < 8; j++) idx[j] = nx[j];
                }
            }
            // store rounded + stats on the rounded values
            if constexpr (VPL == 2) {
                const u16 r0 = f2bf(acc[0]);
                const u16 r1 = f2bf(acc[1]);
                *(u32*)&out[(size_t)n * C + 2 * l] = (u32)r0 | ((u32)r1 << 16);
                const float f0 = bf2f(r0), f1 = bf2f(r1);
                ss[0] += f0; qq[0] += f0 * f0;
                ss[1] += f1; qq[1] += f1 * f1;
            } else {
                const u16 r = f2bf(acc[0]);
                out[(size_t)n * C + l] = r;
                const float f = bf2f(r);
                ss[0] += f; qq[0] += f * f;
            }
        }
    }

    // block reduce across the 4 waves, one atomic per channel per block
#pragma unroll
    for (int v = 0; v < VPL; v++) {
        red[wv][l][2 * v] = ss[v];
        red[wv][l][2 * v + 1] = qq[v];
    }
    __syncthreads();
    if (wv == 0) {
#pragma unroll
        for (int v = 0; v < VPL; v++) {
            float a = 0.f, b = 0.f;
#pragma unroll
            for (int w2 = 0; w2 < 4; w2++) {
                a += red[w2][l][2 * v];
                b += red[w2][l][2 * v + 1];
            }
            const int ch = (VPL == 2) ? (2 * l + v) : l;
            atomAddF(&sum[ch], a);
            atomAddF(&sumsq[ch], b);
        }
    }
}

extern "C" void kernel_launch(void* const* d_in, const int* in_sizes, int n_in,
                              void* d_out, int out_size, void* d_ws, size_t ws_size,
                              hipStream_t stream)
{
    const float* x   = (const float*)d_in[0];
    const int*   ei  = (const int*)d_in[1];
    const float* w1a = (const float*)d_in[2];
    // d_in[3] = b1a: cancelled by BN
    const float* g1  = (const float*)d_in[4];
    const float* be1 = (const float*)d_in[5];
    const float* w1b = (const float*)d_in[6];
    const float* b1b = (const float*)d_in[7];
    const float* w2a = (const float*)d_in[8];
    // d_in[9] = b2a: cancelled by BN
    const float* g2  = (const float*)d_in[10];
    const float* be2 = (const float*)d_in[11];
    const float* w2b = (const float*)d_in[12];
    const float* b2b = (const float*)d_in[13];
    float* out = (float*)d_out;

    const int N = in_sizes[0] / 128;   // 50000
    const int E = in_sizes[1] / 2;     // 800000

    // ---- workspace layout ----
    u16* buf1 = (u16*)d_ws;                      // N*128 bf16 : p1, then h1
    u16* buf2 = buf1 + (size_t)N * 128;          // N*128 bf16 : s1, then p2|s2
    float* stats = (float*)(buf2 + (size_t)N * 128);  // 1024 floats
    float* sum1 = stats,       *sq1 = stats + 128;
    float* sum2 = stats + 256, *sq2 = stats + 320;
    int* cnt    = (int*)(stats + 1024);          // N
    int* off    = cnt + N;                       // N+1
    int* cursor = off + N + 1;                   // N
    int* srcs   = cursor + N;                    // E
    int* bsum   = srcs + E;                      // 256
    int* bpre   = bsum + 256;                    // 256
    short* w1af = (short*)(bpre + 256);          // 128*128
    short* w1bf = w1af + 128 * 128;              // 128*128
    short* w2af = w1bf + 128 * 128;              // 128*64
    short* w2bf = w2af + 128 * 64;               // 64*64
    u16* p1 = buf1;
    u16* s1 = buf2;
    u16* h1 = buf1;                    // reuse: p1 dead after segsum1
    u16* p2 = buf2;                    // reuse: s1 dead after mgemm2 (N*64)
    u16* s2 = buf2 + (size_t)N * 64;   // upper half

    hipMemsetAsync(stats, 0, 1024 * sizeof(float) + (size_t)N * sizeof(int), stream);

    const int G1 = (N + 255) / 256;
    const int gb = (N + 63) / 64;      // BM=64 -> 782 blocks
    const int gs = (N + 31) / 32;      // segsum: 4 waves x 8 nodes per block
    const float invN = 1.f / N;

    // ---- CSR build ----
    hist_k<<<1024, 256, 0, stream>>>(ei, cnt, E);
    bsum_k<<<G1, 256, 0, stream>>>(cnt, bsum, N);
    bscan_k<<<1, 256, 0, stream>>>(bsum, bpre, G1);
    offs_k<<<G1, 256, 0, stream>>>(cnt, bpre, off, cursor, N, E);
    fill_k<<<1024, 256, 0, stream>>>(ei, cursor, srcs, E);

    // ---- weight prep (one launch for all four) ----
    wprep4_k<<<22, 256, 0, stream>>>(w1a, w1b, w2a, w2b, w1af, w1bf, w2af, w2bf);

    // ---- Layer 1 ----
    mgemm<128, 128, false, false, false, false, false, true>
        <<<gb, 256, 0, stream>>>(x, w1af, nullptr, nullptr, nullptr, nullptr,
                                 0.f, nullptr, p1, N);
    segsum_bf<128><<<gs, 256, 0, stream>>>(p1, off, srcs, s1, sum1, sq1, N);
    mgemm<128, 128, true, true, true, true, false, true>
        <<<gb, 256, 0, stream>>>(s1, w1bf, sum1, sq1, g1, be1, invN, b1b, h1, N);

    // ---- Layer 2 (aggregate after projecting to 64ch) ----
    mgemm<128, 64, true, false, false, false, false, true>
        <<<gb, 256, 0, stream>>>(h1, w2af, nullptr, nullptr, nullptr, nullptr,
                                 0.f, nullptr, p2, N);
    segsum_bf<64><<<gs, 256, 0, stream>>>(p2, off, srcs, s2, sum2, sq2, N);
    mgemm<64, 64, true, true, true, false, true, false>
        <<<gb, 256, 0, stream>>>(s2, w2bf, sum2, sq2, g2, be2, invN, b2b, out, N);
}